// Round 2
// baseline (776.385 us; speedup 1.0000x reference)
//
#include <hip/hip_runtime.h>

#define NEV   1000000
#define POUT  4096
#define PIN   16384

// d_ws float-index layout:
//   [SEG_OFF .. +4100)   segment offsets (int), seg[p]=first e with eio[e]>=p, seg[4096]=NEV
//   [W2T_OFF .. +4096)   W2 transposed: W2T[ij*64+k] = W2[k*64+ij]
//   [FT_OFF  .. +512K)   featT[p*32 + (b*8+i)] = features[(b*8+i)*PIN + p]
#define SEG_OFF   0
#define W2T_OFF   4160
#define FT_OFF    8256
#define FT_FLOATS (32 * PIN)
#define PREP_THREADS 1000192   // 3907 * 256

__global__ __launch_bounds__(256) void prep_k(const float* __restrict__ f,
                                              const float* __restrict__ W2,
                                              const int* __restrict__ eio,
                                              float* __restrict__ ws,
                                              int mode) {
    const int tid = blockIdx.x * 256 + threadIdx.x;
    int* seg = (int*)ws + SEG_OFF;
    if (tid < 4096) {                       // W2 transpose (modes 0,1)
        const int k = tid >> 6, ij = tid & 63;
        ws[W2T_OFF + ij * 64 + k] = W2[tid];
    }
    if (mode == 0) {                        // feature transpose
        for (int i = tid; i < FT_FLOATS; i += PREP_THREADS) {
            const int c = i >> 14, pp = i & (PIN - 1);
            ws[FT_OFF + pp * 32 + c] = f[i];
        }
    }
    if (tid < NEV) {                        // segment boundary scan (eio sorted)
        const int cur = eio[tid];
        const int prev = (tid == 0) ? -1 : eio[tid - 1];
        for (int q = prev + 1; q <= cur; ++q) seg[q] = tid;
        if (tid == NEV - 1) {
            for (int q = cur + 1; q <= POUT; ++q) seg[q] = NEV;
        }
    }
}

// One wave per output segment. All weight reads are wave-uniform -> compiler
// promotes to s_load/SGPR operands; no LDS anywhere in this kernel.
template <int MODE>   // 0: seg+W2T+featT in ws; 1: seg+W2T only; 2: no ws
__global__ __launch_bounds__(64) void quadconv_k(
    const float* __restrict__ features,
    const float* __restrict__ eval_locs,
    const float* __restrict__ quad_weights,
    const float* __restrict__ W0,
    const float* __restrict__ W1,
    const float* __restrict__ W2,
    const int* __restrict__ eio,
    const int* __restrict__ eii,
    const float* __restrict__ ws,
    float* __restrict__ out)               // (4, 8, 4096)
{
    const int lane = threadIdx.x;
    const int p = blockIdx.x;

    int start, end;
    if constexpr (MODE <= 1) {
        const int* seg = (const int*)ws + SEG_OFF;
        start = seg[p];
        end = seg[p + 1];
    } else {
        int lo = 0, hi = NEV;
        while (lo < hi) { int m = (lo + hi) >> 1; if (eio[m] < p) lo = m + 1; else hi = m; }
        start = lo; hi = NEV;
        while (lo < hi) { int m = (lo + hi) >> 1; if (eio[m] <= p) lo = m + 1; else hi = m; }
        end = lo;
    }

    float acc[32];   // acc[b*8+j]
    #pragma unroll
    for (int i = 0; i < 32; ++i) acc[i] = 0.f;

    for (int e = start + lane; e < end; e += 64) {
        const float2 x = ((const float2*)eval_locs)[e];
        const int ii = eii[e];

        const float r2 = x.x * x.x + x.y * x.y;
        const float dd = 1.0f - 1048576.0f * r2 * r2;          // 1 - DECAY*r4 >= 0.329
        const float w = __expf(1.0f - 1.0f / dd) * quad_weights[ii];

        // layers 1+2 fused (weights via SGPR): h1[j] = sum_k sin(x.W0[:,k]) * W1[k][j]
        float h1[64];
        #pragma unroll
        for (int j = 0; j < 64; ++j) h1[j] = 0.f;

        #pragma unroll 1
        for (int k4 = 0; k4 < 64; k4 += 4) {
            const float4 wa = *(const float4*)(W0 + k4);        // W0[0][k4..]
            const float4 wb = *(const float4*)(W0 + 64 + k4);   // W0[1][k4..]
            const float h0a = __sinf(fmaf(x.x, wa.x, x.y * wb.x));
            const float h0b = __sinf(fmaf(x.x, wa.y, x.y * wb.y));
            const float h0c = __sinf(fmaf(x.x, wa.z, x.y * wb.z));
            const float h0d = __sinf(fmaf(x.x, wa.w, x.y * wb.w));
            const float4* r0 = (const float4*)(W1 + ((k4 + 0) << 6));
            const float4* r1 = (const float4*)(W1 + ((k4 + 1) << 6));
            const float4* r2p = (const float4*)(W1 + ((k4 + 2) << 6));
            const float4* r3 = (const float4*)(W1 + ((k4 + 3) << 6));
            #pragma unroll
            for (int q = 0; q < 16; ++q) {
                const float4 v0 = r0[q], v1 = r1[q], v2 = r2p[q], v3 = r3[q];
                h1[4*q+0] = fmaf(h0d, v3.x, fmaf(h0c, v2.x, fmaf(h0b, v1.x, fmaf(h0a, v0.x, h1[4*q+0]))));
                h1[4*q+1] = fmaf(h0d, v3.y, fmaf(h0c, v2.y, fmaf(h0b, v1.y, fmaf(h0a, v0.y, h1[4*q+1]))));
                h1[4*q+2] = fmaf(h0d, v3.z, fmaf(h0c, v2.z, fmaf(h0b, v1.z, fmaf(h0a, v0.z, h1[4*q+2]))));
                h1[4*q+3] = fmaf(h0d, v3.w, fmaf(h0c, v2.w, fmaf(h0b, v1.w, fmaf(h0a, v0.w, h1[4*q+3]))));
            }
        }
        #pragma unroll
        for (int j = 0; j < 64; ++j) h1[j] = __sinf(h1[j]);

        // layer 3 + einsum: filt[i][j] = sum_k h1[k]*W2[k][i*8+j]; acc[b][j] += w*g[b][i]*filt[i][j]
        #pragma unroll 1
        for (int i = 0; i < 8; ++i) {
            float g0, g1, g2, g3;
            if constexpr (MODE == 0) {
                const float* gp = ws + FT_OFF + ii * 32 + i;   // one 128B line per eval
                g0 = gp[0]; g1 = gp[8]; g2 = gp[16]; g3 = gp[24];
            } else {
                g0 = features[(0 * 8 + i) * PIN + ii];
                g1 = features[(1 * 8 + i) * PIN + ii];
                g2 = features[(2 * 8 + i) * PIN + ii];
                g3 = features[(3 * 8 + i) * PIN + ii];
            }
            g0 *= w; g1 *= w; g2 *= w; g3 *= w;
            #pragma unroll
            for (int j = 0; j < 8; ++j) {
                float s0 = 0.f, s1 = 0.f, s2 = 0.f, s3 = 0.f;
                if constexpr (MODE <= 1) {
                    const float4* row = (const float4*)(ws + W2T_OFF + ((i * 8 + j) << 6));
                    #pragma unroll
                    for (int q = 0; q < 16; ++q) {
                        const float4 wv = row[q];
                        s0 = fmaf(h1[4*q+0], wv.x, s0);
                        s1 = fmaf(h1[4*q+1], wv.y, s1);
                        s2 = fmaf(h1[4*q+2], wv.z, s2);
                        s3 = fmaf(h1[4*q+3], wv.w, s3);
                    }
                } else {
                    #pragma unroll
                    for (int q = 0; q < 16; ++q) {
                        s0 = fmaf(h1[4*q+0], W2[(4*q+0)*64 + i*8+j], s0);
                        s1 = fmaf(h1[4*q+1], W2[(4*q+1)*64 + i*8+j], s1);
                        s2 = fmaf(h1[4*q+2], W2[(4*q+2)*64 + i*8+j], s2);
                        s3 = fmaf(h1[4*q+3], W2[(4*q+3)*64 + i*8+j], s3);
                    }
                }
                const float fv = (s0 + s1) + (s2 + s3);
                acc[0*8+j] = fmaf(g0, fv, acc[0*8+j]);
                acc[1*8+j] = fmaf(g1, fv, acc[1*8+j]);
                acc[2*8+j] = fmaf(g2, fv, acc[2*8+j]);
                acc[3*8+j] = fmaf(g3, fv, acc[3*8+j]);
            }
        }
    }

    // wave-level reduction; one wave owns segment p -> no atomics
    float myval = 0.f;
    #pragma unroll
    for (int v = 0; v < 32; ++v) {
        float s = acc[v];
        s += __shfl_xor(s, 1, 64);
        s += __shfl_xor(s, 2, 64);
        s += __shfl_xor(s, 4, 64);
        s += __shfl_xor(s, 8, 64);
        s += __shfl_xor(s, 16, 64);
        s += __shfl_xor(s, 32, 64);
        if (lane == v) myval = s;
    }
    if (lane < 32) {
        const int b = lane >> 3, j = lane & 7;
        out[b * (8 * POUT) + j * POUT + p] = myval;
    }
}

extern "C" void kernel_launch(void* const* d_in, const int* in_sizes, int n_in,
                              void* d_out, int out_size, void* d_ws, size_t ws_size,
                              hipStream_t stream) {
    const float* features  = (const float*)d_in[0];
    const float* eval_locs = (const float*)d_in[1];
    const float* qw        = (const float*)d_in[2];
    const float* W0        = (const float*)d_in[3];
    const float* W1        = (const float*)d_in[4];
    const float* W2        = (const float*)d_in[5];
    const int*   eio       = (const int*)d_in[6];
    const int*   eii       = (const int*)d_in[7];
    float* out = (float*)d_out;
    float* ws  = (float*)d_ws;

    const size_t need0 = (size_t)(FT_OFF + FT_FLOATS) * 4;
    const size_t need1 = (size_t)(W2T_OFF + 4096) * 4;
    const int mode = (ws_size >= need0) ? 0 : (ws_size >= need1 ? 1 : 2);

    if (mode <= 1) {
        prep_k<<<PREP_THREADS / 256, 256, 0, stream>>>(features, W2, eio, ws, mode);
    }
    switch (mode) {
        case 0: quadconv_k<0><<<POUT, 64, 0, stream>>>(features, eval_locs, qw, W0, W1, W2, eio, eii, ws, out); break;
        case 1: quadconv_k<1><<<POUT, 64, 0, stream>>>(features, eval_locs, qw, W0, W1, W2, eio, eii, ws, out); break;
        default: quadconv_k<2><<<POUT, 64, 0, stream>>>(features, eval_locs, qw, W0, W1, W2, eio, eii, ws, out); break;
    }
}

// Round 4
// 211.015 us; speedup vs baseline: 3.6793x; 3.6793x over previous
//
#include <hip/hip_runtime.h>

#define NEV   1000000
#define POUT  4096
#define PIN   16384

typedef __bf16 bf16x8 __attribute__((ext_vector_type(8)));
typedef float  f32x16 __attribute__((ext_vector_type(16)));

#define SEG_OFF   0
#define FT_OFF    4160
#define FT_FLOATS (32 * PIN)

// 3-product split-bf16 MFMA: acc += (Ahi+Alo)(Bhi+Blo), dropping Alo*Blo
#define GEMM3(accv, ahi_, alo_, bhi_, blo_)                                          \
    accv = __builtin_amdgcn_mfma_f32_32x32x16_bf16(ahi_, bhi_, accv, 0, 0, 0);       \
    accv = __builtin_amdgcn_mfma_f32_32x32x16_bf16(ahi_, blo_, accv, 0, 0, 0);       \
    accv = __builtin_amdgcn_mfma_f32_32x32x16_bf16(alo_, bhi_, accv, 0, 0, 0);

__global__ __launch_bounds__(256) void prep_k(const float* __restrict__ f,
                                              const int* __restrict__ eio,
                                              float* __restrict__ ws) {
    const int tid = blockIdx.x * 256 + threadIdx.x;
    const int nth = gridDim.x * 256;
    int* seg = (int*)ws + SEG_OFF;
    // featT[p*32 + c] = features[c*PIN + p]
    for (int i = tid; i < FT_FLOATS; i += nth) {
        const int c = i >> 14, pp = i & (PIN - 1);
        ws[FT_OFF + pp * 32 + c] = f[i];
    }
    // segment offsets from sorted eval_idx_out
    for (int e = tid; e < NEV; e += nth) {
        const int cur = eio[e];
        const int prev = (e == 0) ? -1 : eio[e - 1];
        for (int q = prev + 1; q <= cur; ++q) seg[q] = e;
        if (e == NEV - 1) { for (int q = cur + 1; q <= POUT; ++q) seg[q] = NEV; }
    }
}

template <int MODE>   // 0: seg+featT in ws; 2: no ws (fallback)
__global__ __launch_bounds__(256, 1) void quadconv_mfma_k(
    const float* __restrict__ features,
    const float* __restrict__ eval_locs,
    const float* __restrict__ quad_weights,
    const float* __restrict__ W0,
    const float* __restrict__ W1,
    const float* __restrict__ W2,
    const int* __restrict__ eio,
    const int* __restrict__ eii,
    const float* __restrict__ ws,
    float* __restrict__ out)               // (4, 8, 4096)
{
    __shared__ unsigned int ldsbuf[4][64 * 33];   // per-wave h1 relayout scratch
    const int tid  = threadIdx.x;
    const int wid  = tid >> 6;
    const int lane = tid & 63;
    const int n    = lane & 31;    // eval column within tile / M row within A
    const int hl   = lane >> 5;    // k-slice half
    const int p    = blockIdx.x * 4 + wid;          // this wave's output segment

    int start, end;
    if constexpr (MODE == 0) {
        const int* seg = (const int*)ws + SEG_OFF;
        start = seg[p]; end = seg[p + 1];
    } else {
        int lo = 0, hi = NEV;
        while (lo < hi) { int m = (lo + hi) >> 1; if (eio[m] < p) lo = m + 1; else hi = m; }
        start = lo; hi = NEV;
        while (lo < hi) { int m = (lo + hi) >> 1; if (eio[m] <= p) lo = m + 1; else hi = m; }
        end = lo;
    }

    // ---- A-fragments (W1^T, W2^T as M=64 x K=64), split hi/lo, resident all kernel ----
    // A[m][k] layout: m = (lane&31)+32*mb, k = 8*(lane>>5)+e+16*t  ->  W[k*64+m]
    bf16x8 a1hi[2][4], a1lo[2][4], a2hi[2][4], a2lo[2][4];
    #pragma unroll
    for (int mb = 0; mb < 2; ++mb) {
        #pragma unroll
        for (int t = 0; t < 4; ++t) {
            #pragma unroll
            for (int e = 0; e < 8; ++e) {
                const int k = 8 * hl + e + 16 * t;
                const int m = n + 32 * mb;
                const float v1 = W1[k * 64 + m];
                const float v2 = W2[k * 64 + m];
                const __bf16 h1b = (__bf16)v1;
                const __bf16 h2b = (__bf16)v2;
                a1hi[mb][t][e] = h1b;  a1lo[mb][t][e] = (__bf16)(v1 - (float)h1b);
                a2hi[mb][t][e] = h2b;  a2lo[mb][t][e] = (__bf16)(v2 - (float)h2b);
            }
        }
    }

    float accout[4][4];            // [b][j_local], j = 4*hl + j_local
    #pragma unroll
    for (int b = 0; b < 4; ++b)
        #pragma unroll
        for (int a = 0; a < 4; ++a) accout[b][a] = 0.f;

    unsigned int* L = ldsbuf[wid];
    const int nt = (end - start + 31) >> 5;

    for (int tile = 0; tile < nt; ++tile) {
        const int e  = start + tile * 32 + n;
        const bool valid = (e < end);
        const int ec = valid ? e : (end - 1);
        const float2 x = ((const float2*)eval_locs)[ec];
        const int ii = eii[ec];

        const float r2 = x.x * x.x + x.y * x.y;
        const float dd = 1.0f - 1048576.0f * r2 * r2;      // 1 - DECAY*r4 >= 0.33
        float wgt = __expf(1.0f - 1.0f / dd) * quad_weights[ii];
        if (!valid) wgt = 0.f;

        // ---- GEMM1: H1pre^T(64xN) = W1^T @ H0^T ; B built in-register ----
        f32x16 acc1[2];
        #pragma unroll
        for (int mb = 0; mb < 2; ++mb)
            #pragma unroll
            for (int r = 0; r < 16; ++r) acc1[mb][r] = 0.f;

        #pragma unroll
        for (int t = 0; t < 4; ++t) {
            const int k0 = 16 * t + 8 * hl;
            const float4 wa0 = *(const float4*)(W0 + k0);
            const float4 wa1 = *(const float4*)(W0 + k0 + 4);
            const float4 wb0 = *(const float4*)(W0 + 64 + k0);
            const float4 wb1 = *(const float4*)(W0 + 64 + k0 + 4);
            bf16x8 bhi, blo;
            {
                float s;  __bf16 hb;
                s = __sinf(fmaf(x.x, wa0.x, x.y * wb0.x)); hb = (__bf16)s; bhi[0] = hb; blo[0] = (__bf16)(s - (float)hb);
                s = __sinf(fmaf(x.x, wa0.y, x.y * wb0.y)); hb = (__bf16)s; bhi[1] = hb; blo[1] = (__bf16)(s - (float)hb);
                s = __sinf(fmaf(x.x, wa0.z, x.y * wb0.z)); hb = (__bf16)s; bhi[2] = hb; blo[2] = (__bf16)(s - (float)hb);
                s = __sinf(fmaf(x.x, wa0.w, x.y * wb0.w)); hb = (__bf16)s; bhi[3] = hb; blo[3] = (__bf16)(s - (float)hb);
                s = __sinf(fmaf(x.x, wa1.x, x.y * wb1.x)); hb = (__bf16)s; bhi[4] = hb; blo[4] = (__bf16)(s - (float)hb);
                s = __sinf(fmaf(x.x, wa1.y, x.y * wb1.y)); hb = (__bf16)s; bhi[5] = hb; blo[5] = (__bf16)(s - (float)hb);
                s = __sinf(fmaf(x.x, wa1.z, x.y * wb1.z)); hb = (__bf16)s; bhi[6] = hb; blo[6] = (__bf16)(s - (float)hb);
                s = __sinf(fmaf(x.x, wa1.w, x.y * wb1.w)); hb = (__bf16)s; bhi[7] = hb; blo[7] = (__bf16)(s - (float)hb);
            }
            #pragma unroll
            for (int mb = 0; mb < 2; ++mb) { GEMM3(acc1[mb], a1hi[mb][t], a1lo[mb][t], bhi, blo); }
        }

        // ---- h1 = sin(.), split, relayout C->B via per-wave LDS ----
        // C layout: col n = lane&31, row j = (r&3) + 8*(r>>2) + 4*hl + 32*mb
        #pragma unroll
        for (int mb = 0; mb < 2; ++mb) {
            #pragma unroll
            for (int r = 0; r < 16; ++r) {
                const int j = (r & 3) + 8 * (r >> 2) + 4 * hl + 32 * mb;
                const float s = __sinf(acc1[mb][r]);
                const __bf16 hb = (__bf16)s;
                const __bf16 lb = (__bf16)(s - (float)hb);
                const unsigned int u =
                    ((unsigned int)__builtin_bit_cast(unsigned short, hb) << 16) |
                     (unsigned int)__builtin_bit_cast(unsigned short, lb);
                L[j * 33 + n] = u;
            }
        }

        // gathered features * w  (loaded here so VMEM latency hides under GEMM2)
        float wg[4][8];
        if constexpr (MODE == 0) {
            const float4* gp = (const float4*)(ws + FT_OFF + ii * 32);
            #pragma unroll
            for (int b = 0; b < 4; ++b) {
                const float4 u0 = gp[2 * b], u1 = gp[2 * b + 1];
                wg[b][0] = wgt * u0.x; wg[b][1] = wgt * u0.y; wg[b][2] = wgt * u0.z; wg[b][3] = wgt * u0.w;
                wg[b][4] = wgt * u1.x; wg[b][5] = wgt * u1.y; wg[b][6] = wgt * u1.z; wg[b][7] = wgt * u1.w;
            }
        } else {
            #pragma unroll
            for (int b = 0; b < 4; ++b)
                #pragma unroll
                for (int i = 0; i < 8; ++i)
                    wg[b][i] = wgt * features[(b * 8 + i) * PIN + ii];
        }

        // ---- GEMM2: filt^T(64xN) = W2^T @ H1^T ; B from LDS ----
        f32x16 acc2[2];
        #pragma unroll
        for (int mb = 0; mb < 2; ++mb)
            #pragma unroll
            for (int r = 0; r < 16; ++r) acc2[mb][r] = 0.f;

        #pragma unroll
        for (int t = 0; t < 4; ++t) {
            bf16x8 bhi, blo;
            #pragma unroll
            for (int q = 0; q < 8; ++q) {
                const unsigned int u = L[(16 * t + 8 * hl + q) * 33 + n];
                bhi[q] = __builtin_bit_cast(__bf16, (unsigned short)(u >> 16));
                blo[q] = __builtin_bit_cast(__bf16, (unsigned short)(u & 0xffffu));
            }
            #pragma unroll
            for (int mb = 0; mb < 2; ++mb) { GEMM3(acc2[mb], a2hi[mb][t], a2lo[mb][t], bhi, blo); }
        }

        // ---- einsum: accout[b][j_local] += wg[b][i] * filt[i][j] ----
        // acc2 row m = ij: i = (r>>2)+4*mb, j = 4*hl + (r&3)
        #pragma unroll
        for (int mb = 0; mb < 2; ++mb) {
            #pragma unroll
            for (int r = 0; r < 16; ++r) {
                const float fv = acc2[mb][r];
                const int i = (r >> 2) + 4 * mb;
                const int a = r & 3;
                accout[0][a] = fmaf(wg[0][i], fv, accout[0][a]);
                accout[1][a] = fmaf(wg[1][i], fv, accout[1][a]);
                accout[2][a] = fmaf(wg[2][i], fv, accout[2][a]);
                accout[3][a] = fmaf(wg[3][i], fv, accout[3][a]);
            }
        }
    }

    // ---- reduce over the 32 eval columns (xor 1..16 spans each 32-lane half) ----
    #pragma unroll
    for (int b = 0; b < 4; ++b) {
        #pragma unroll
        for (int a = 0; a < 4; ++a) {
            float v = accout[b][a];
            v += __shfl_xor(v, 1);
            v += __shfl_xor(v, 2);
            v += __shfl_xor(v, 4);
            v += __shfl_xor(v, 8);
            v += __shfl_xor(v, 16);
            if (n == 0) {
                const int j = 4 * hl + a;
                out[b * (8 * POUT) + j * POUT + p] = v;
            }
        }
    }
}

extern "C" void kernel_launch(void* const* d_in, const int* in_sizes, int n_in,
                              void* d_out, int out_size, void* d_ws, size_t ws_size,
                              hipStream_t stream) {
    const float* features  = (const float*)d_in[0];
    const float* eval_locs = (const float*)d_in[1];
    const float* qw        = (const float*)d_in[2];
    const float* W0        = (const float*)d_in[3];
    const float* W1        = (const float*)d_in[4];
    const float* W2        = (const float*)d_in[5];
    const int*   eio       = (const int*)d_in[6];
    const int*   eii       = (const int*)d_in[7];
    float* out = (float*)d_out;
    float* ws  = (float*)d_ws;

    const size_t need0 = (size_t)(FT_OFF + FT_FLOATS) * 4;
    if (ws_size >= need0) {
        prep_k<<<1024, 256, 0, stream>>>(features, eio, ws);
        quadconv_mfma_k<0><<<POUT / 4, 256, 0, stream>>>(features, eval_locs, qw, W0, W1, W2,
                                                         eio, eii, ws, out);
    } else {
        quadconv_mfma_k<2><<<POUT / 4, 256, 0, stream>>>(features, eval_locs, qw, W0, W1, W2,
                                                         eio, eii, ws, out);
    }
}

// Round 5
// 152.302 us; speedup vs baseline: 5.0977x; 1.3855x over previous
//
#include <hip/hip_runtime.h>

#define NEV   1000000
#define POUT  4096
#define PIN   16384

typedef __bf16 bf16x8 __attribute__((ext_vector_type(8)));
typedef float  f32x16 __attribute__((ext_vector_type(16)));

#define SEG_OFF   0
#define FT_OFF    4160
#define FT_FLOATS (32 * PIN)

#define LH1_STRIDE 66   // u32/eval-row (64 j + 2 pad): 264B -> 8B-aligned b64, 2-way banks
#define LWG_STRIDE 34   // u32/eval-row (32 bi + 2 pad)
#define LH1_SIZE (32 * LH1_STRIDE)
#define LWG_SIZE (32 * LWG_STRIDE)

// 3-product split-bf16 MFMA: acc += (Ahi+Alo)(Bhi+Blo), dropping Alo*Blo (~2^-18 rel)
#define GEMM3(accv, ahi_, alo_, bhi_, blo_)                                          \
    accv = __builtin_amdgcn_mfma_f32_32x32x16_bf16(ahi_, bhi_, accv, 0, 0, 0);       \
    accv = __builtin_amdgcn_mfma_f32_32x32x16_bf16(ahi_, blo_, accv, 0, 0, 0);       \
    accv = __builtin_amdgcn_mfma_f32_32x32x16_bf16(alo_, bhi_, accv, 0, 0, 0);

__global__ __launch_bounds__(256) void prep_k(const float* __restrict__ f,
                                              const int* __restrict__ eio,
                                              float* __restrict__ ws) {
    const int bid = blockIdx.x, t = threadIdx.x;
    if (bid < 512) {                     // coalesced featT transpose: 32 p-rows/block
        __shared__ float tile[32][33];
        const int p0 = bid * 32;
        #pragma unroll
        for (int rep = 0; rep < 4; ++rep) {
            const int idx = rep * 256 + t;
            const int c = idx >> 5, pl = idx & 31;
            tile[pl][c] = f[c * PIN + p0 + pl];          // 128B-coalesced reads
        }
        __syncthreads();
        #pragma unroll
        for (int rep = 0; rep < 4; ++rep) {
            const int idx = rep * 256 + t;
            const int pl = idx >> 5, c = idx & 31;
            ws[FT_OFF + (p0 + pl) * 32 + c] = tile[pl][c];   // coalesced writes
        }
    } else {                             // segment offsets from sorted eval_idx_out
        int* seg = (int*)ws + SEG_OFF;
        const int base = (bid - 512) * 1024 + t * 4;
        #pragma unroll
        for (int u = 0; u < 4; ++u) {
            const int e = base + u;
            if (e < NEV) {
                const int cur = eio[e];
                const int prev = (e == 0) ? -1 : eio[e - 1];
                for (int q = prev + 1; q <= cur; ++q) seg[q] = e;
                if (e == NEV - 1) { for (int q = cur + 1; q <= POUT; ++q) seg[q] = NEV; }
            }
        }
    }
}

template <int MODE>   // 0: seg+featT in ws; 2: no ws (fallback)
__global__ __launch_bounds__(256, 2) void quadconv_mfma_k(
    const float* __restrict__ features,
    const float* __restrict__ eval_locs,
    const float* __restrict__ quad_weights,
    const float* __restrict__ W0,
    const float* __restrict__ W1,
    const float* __restrict__ W2,
    const int* __restrict__ eio,
    const int* __restrict__ eii,
    const float* __restrict__ ws,
    float* __restrict__ out)               // (4, 8, 4096)
{
    __shared__ unsigned int lh1[4][LH1_SIZE];   // per-wave h1 relayout (hi<<16|lo)
    __shared__ unsigned int lwg[4][LWG_SIZE];   // per-wave wg relayout (hi<<16|lo)
    const int tid  = threadIdx.x;
    const int wid  = tid >> 6;
    const int lane = tid & 63;
    const int n    = lane & 31;    // eval column / A-row / (b,i) column
    const int hl   = lane >> 5;
    const int p    = blockIdx.x * 4 + wid;      // this wave's output segment

    int start, end;
    if constexpr (MODE == 0) {
        const int* seg = (const int*)ws + SEG_OFF;
        start = seg[p]; end = seg[p + 1];
    } else {
        int lo = 0, hi = NEV;
        while (lo < hi) { int m = (lo + hi) >> 1; if (eio[m] < p) lo = m + 1; else hi = m; }
        start = lo; hi = NEV;
        while (lo < hi) { int m = (lo + hi) >> 1; if (eio[m] <= p) lo = m + 1; else hi = m; }
        end = lo;
    }

    // ---- resident A-fragments: W1^T only (M=64 x K=64), hi/lo split ----
    // A[m][k]: m=(lane&31)+32*mb, k=8*(lane>>5)+e+16*t -> W1[k*64+m]
    bf16x8 a1hi[2][4], a1lo[2][4];
    #pragma unroll
    for (int mb = 0; mb < 2; ++mb) {
        #pragma unroll
        for (int t = 0; t < 4; ++t) {
            #pragma unroll
            for (int e = 0; e < 8; ++e) {
                const int k = 8 * hl + e + 16 * t;
                const float v1 = W1[k * 64 + n + 32 * mb];
                const __bf16 h1b = (__bf16)v1;
                a1hi[mb][t][e] = h1b;
                a1lo[mb][t][e] = (__bf16)(v1 - (float)h1b);
            }
        }
    }

    // persistent accumulator T[khid, (b,i)] (64x32), accumulated over ALL tiles
    f32x16 T[2];
    #pragma unroll
    for (int mb = 0; mb < 2; ++mb)
        #pragma unroll
        for (int r = 0; r < 16; ++r) T[mb][r] = 0.f;

    unsigned int* Lh = lh1[wid];
    unsigned int* Lw = lwg[wid];
    const int nt = (end - start + 31) >> 5;

    for (int tile = 0; tile < nt; ++tile) {
        const int e  = start + tile * 32 + n;
        const bool valid = (e < end);
        const int ec = valid ? e : (end - 1);
        const float2 x = ((const float2*)eval_locs)[ec];
        const int ii = eii[ec];

        const float r2 = x.x * x.x + x.y * x.y;
        const float dd = 1.0f - 1048576.0f * r2 * r2;      // 1 - DECAY*r4 >= 0.33
        float wgt = __expf(1.0f - 1.0f / dd) * quad_weights[ii];
        if (!valid) wgt = 0.f;

        // ---- GEMM1: H1pre^T(64xN=32evals) = W1^T @ H0^T ; B built in-register ----
        f32x16 acc1[2];
        #pragma unroll
        for (int mb = 0; mb < 2; ++mb)
            #pragma unroll
            for (int r = 0; r < 16; ++r) acc1[mb][r] = 0.f;

        #pragma unroll
        for (int t = 0; t < 4; ++t) {
            const int k0 = 16 * t + 8 * hl;
            const float4 wa0 = *(const float4*)(W0 + k0);
            const float4 wa1 = *(const float4*)(W0 + k0 + 4);
            const float4 wb0 = *(const float4*)(W0 + 64 + k0);
            const float4 wb1 = *(const float4*)(W0 + 64 + k0 + 4);
            bf16x8 bhi, blo;
            {
                float s;  __bf16 hb;
                s = __sinf(fmaf(x.x, wa0.x, x.y * wb0.x)); hb = (__bf16)s; bhi[0] = hb; blo[0] = (__bf16)(s - (float)hb);
                s = __sinf(fmaf(x.x, wa0.y, x.y * wb0.y)); hb = (__bf16)s; bhi[1] = hb; blo[1] = (__bf16)(s - (float)hb);
                s = __sinf(fmaf(x.x, wa0.z, x.y * wb0.z)); hb = (__bf16)s; bhi[2] = hb; blo[2] = (__bf16)(s - (float)hb);
                s = __sinf(fmaf(x.x, wa0.w, x.y * wb0.w)); hb = (__bf16)s; bhi[3] = hb; blo[3] = (__bf16)(s - (float)hb);
                s = __sinf(fmaf(x.x, wa1.x, x.y * wb1.x)); hb = (__bf16)s; bhi[4] = hb; blo[4] = (__bf16)(s - (float)hb);
                s = __sinf(fmaf(x.x, wa1.y, x.y * wb1.y)); hb = (__bf16)s; bhi[5] = hb; blo[5] = (__bf16)(s - (float)hb);
                s = __sinf(fmaf(x.x, wa1.z, x.y * wb1.z)); hb = (__bf16)s; bhi[6] = hb; blo[6] = (__bf16)(s - (float)hb);
                s = __sinf(fmaf(x.x, wa1.w, x.y * wb1.w)); hb = (__bf16)s; bhi[7] = hb; blo[7] = (__bf16)(s - (float)hb);
            }
            #pragma unroll
            for (int mb = 0; mb < 2; ++mb) { GEMM3(acc1[mb], a1hi[mb][t], a1lo[mb][t], bhi, blo); }
        }

        // ---- h1 = sin(acc1): split hi/lo, pack u32, LDS layout Lh[e][j] ----
        // C layout: col n=eval, row j=(r&3)+8*(r>>2)+4*hl+32*mb; r-quads give 4 consecutive j
        #pragma unroll
        for (int mb = 0; mb < 2; ++mb) {
            #pragma unroll
            for (int rq = 0; rq < 4; ++rq) {
                const int j0 = 8 * rq + 4 * hl + 32 * mb;
                unsigned int u[4];
                #pragma unroll
                for (int s4 = 0; s4 < 4; ++s4) {
                    const float s = __sinf(acc1[mb][4 * rq + s4]);
                    const __bf16 hb = (__bf16)s;
                    const __bf16 lb = (__bf16)(s - (float)hb);
                    u[s4] = ((unsigned int)__builtin_bit_cast(unsigned short, hb) << 16) |
                             (unsigned int)__builtin_bit_cast(unsigned short, lb);
                }
                *(uint2*)&Lh[n * LH1_STRIDE + j0]     = make_uint2(u[0], u[1]);
                *(uint2*)&Lh[n * LH1_STRIDE + j0 + 2] = make_uint2(u[2], u[3]);
            }
        }

        // ---- wg[b,i] = wgt * g[b,i]: this lane packs bi = 16*hl .. +15 ----
        {
            float g[16];
            if constexpr (MODE == 0) {
                const float4* gp = (const float4*)(ws + FT_OFF + ii * 32 + 16 * hl);
                const float4 G0 = gp[0], G1 = gp[1], G2 = gp[2], G3 = gp[3];
                g[0]=G0.x; g[1]=G0.y; g[2]=G0.z; g[3]=G0.w;
                g[4]=G1.x; g[5]=G1.y; g[6]=G1.z; g[7]=G1.w;
                g[8]=G2.x; g[9]=G2.y; g[10]=G2.z; g[11]=G2.w;
                g[12]=G3.x; g[13]=G3.y; g[14]=G3.z; g[15]=G3.w;
            } else {
                #pragma unroll
                for (int v = 0; v < 16; ++v) g[v] = features[(16 * hl + v) * PIN + ii];
            }
            #pragma unroll
            for (int v2 = 0; v2 < 8; ++v2) {
                unsigned int u[2];
                #pragma unroll
                for (int s4 = 0; s4 < 2; ++s4) {
                    const float wv = wgt * g[2 * v2 + s4];
                    const __bf16 hb = (__bf16)wv;
                    const __bf16 lb = (__bf16)(wv - (float)hb);
                    u[s4] = ((unsigned int)__builtin_bit_cast(unsigned short, hb) << 16) |
                             (unsigned int)__builtin_bit_cast(unsigned short, lb);
                }
                *(uint2*)&Lw[n * LWG_STRIDE + 16 * hl + 2 * v2] = make_uint2(u[0], u[1]);
            }
        }

        // ---- GEMM2': T[khid,(b,i)] += h1(64 x e) @ wg(e x 32); K = 32 evals ----
        #pragma unroll
        for (int kt = 0; kt < 2; ++kt) {
            bf16x8 bh, bl;
            #pragma unroll
            for (int q = 0; q < 8; ++q) {
                const unsigned int u = Lw[(16 * kt + 8 * hl + q) * LWG_STRIDE + n];
                bh[q] = __builtin_bit_cast(__bf16, (unsigned short)(u >> 16));
                bl[q] = __builtin_bit_cast(__bf16, (unsigned short)(u & 0xffffu));
            }
            #pragma unroll
            for (int mb = 0; mb < 2; ++mb) {
                bf16x8 ah, al;
                #pragma unroll
                for (int q = 0; q < 8; ++q) {
                    const unsigned int u = Lh[(16 * kt + 8 * hl + q) * LH1_STRIDE + n + 32 * mb];
                    ah[q] = __builtin_bit_cast(__bf16, (unsigned short)(u >> 16));
                    al[q] = __builtin_bit_cast(__bf16, (unsigned short)(u & 0xffffu));
                }
                GEMM3(T[mb], ah, al, bh, bl);
            }
        }
    }

    // ---- epilogue (once per wave): out[b,j] = sum_{khid,i} W2[khid][i*8+j] * T[khid][b*8+i]
    // lane (n,hl) holds T at khid=(r&3)+8*(r>>2)+4*hl+32*mb, col n=(b=n>>3, i=n&7)
    {
        const int i = n & 7, b = n >> 3;
        float pj[8];
        #pragma unroll
        for (int j = 0; j < 8; ++j) pj[j] = 0.f;
        #pragma unroll
        for (int mb = 0; mb < 2; ++mb) {
            #pragma unroll
            for (int r = 0; r < 16; ++r) {
                const int khid = (r & 3) + 8 * (r >> 2) + 4 * hl + 32 * mb;
                const float tv = T[mb][r];
                const float4 w20 = *(const float4*)(W2 + khid * 64 + i * 8);
                const float4 w21 = *(const float4*)(W2 + khid * 64 + i * 8 + 4);
                pj[0] = fmaf(tv, w20.x, pj[0]);
                pj[1] = fmaf(tv, w20.y, pj[1]);
                pj[2] = fmaf(tv, w20.z, pj[2]);
                pj[3] = fmaf(tv, w20.w, pj[3]);
                pj[4] = fmaf(tv, w21.x, pj[4]);
                pj[5] = fmaf(tv, w21.y, pj[5]);
                pj[6] = fmaf(tv, w21.z, pj[6]);
                pj[7] = fmaf(tv, w21.w, pj[7]);
            }
        }
        #pragma unroll
        for (int j = 0; j < 8; ++j) {           // reduce over i (xor 1,2,4) and hl (xor 32)
            float v = pj[j];
            v += __shfl_xor(v, 1);
            v += __shfl_xor(v, 2);
            v += __shfl_xor(v, 4);
            v += __shfl_xor(v, 32);
            pj[j] = v;
        }
        if (i == 0 && hl == 0) {
            #pragma unroll
            for (int j = 0; j < 8; ++j) out[b * (8 * POUT) + j * POUT + p] = pj[j];
        }
    }
}

extern "C" void kernel_launch(void* const* d_in, const int* in_sizes, int n_in,
                              void* d_out, int out_size, void* d_ws, size_t ws_size,
                              hipStream_t stream) {
    const float* features  = (const float*)d_in[0];
    const float* eval_locs = (const float*)d_in[1];
    const float* qw        = (const float*)d_in[2];
    const float* W0        = (const float*)d_in[3];
    const float* W1        = (const float*)d_in[4];
    const float* W2        = (const float*)d_in[5];
    const int*   eio       = (const int*)d_in[6];
    const int*   eii       = (const int*)d_in[7];
    float* out = (float*)d_out;
    float* ws  = (float*)d_ws;

    const size_t need0 = (size_t)(FT_OFF + FT_FLOATS) * 4;
    if (ws_size >= need0) {
        prep_k<<<512 + (NEV + 1023) / 1024, 256, 0, stream>>>(features, eio, ws);
        quadconv_mfma_k<0><<<POUT / 4, 256, 0, stream>>>(features, eval_locs, qw, W0, W1, W2,
                                                         eio, eii, ws, out);
    } else {
        quadconv_mfma_k<2><<<POUT / 4, 256, 0, stream>>>(features, eval_locs, qw, W0, W1, W2,
                                                         eio, eii, ws, out);
    }
}

// Round 8
// 140.180 us; speedup vs baseline: 5.5385x; 1.0865x over previous
//
#include <hip/hip_runtime.h>

#define NEV   1000000
#define POUT  4096
#define PIN   16384

typedef __bf16 bf16x8 __attribute__((ext_vector_type(8)));
typedef float  f32x16 __attribute__((ext_vector_type(16)));

#define SEG_OFF   0
#define FT_OFF    4160
#define FT_FLOATS (32 * PIN)

#define LH_ST 36   // u32 stride, 16B-aligned rows, rotation-dense banks
#define LW_ST 36

#define SEL_HI 0x07060302u   // [a.b2,a.b3 | b.b2,b.b3] -> (hi(b)|hi(a)) pairs
#define SEL_LO 0x05040100u

// pack f32 v into u32: bf16_trunc(v) in high 16, bf16_trunc(v - trunc(v)) in low 16
__device__ __forceinline__ unsigned pack_hl(float v) {
    const unsigned b = __builtin_bit_cast(unsigned, v);
    const float hb = __builtin_bit_cast(float, b & 0xFFFF0000u);
    const float lo = v - hb;
    return __builtin_amdgcn_perm(b, __builtin_bit_cast(unsigned, lo), SEL_HI);
}

// 3-product split-bf16 MFMA: acc += (Ahi+Alo)(Bhi+Blo), dropping Alo*Blo
#define GEMM3(accv, ahi_, alo_, bhi_, blo_)                                          \
    accv = __builtin_amdgcn_mfma_f32_32x32x16_bf16(ahi_, bhi_, accv, 0, 0, 0);       \
    accv = __builtin_amdgcn_mfma_f32_32x32x16_bf16(ahi_, blo_, accv, 0, 0, 0);       \
    accv = __builtin_amdgcn_mfma_f32_32x32x16_bf16(alo_, bhi_, accv, 0, 0, 0);

__global__ __launch_bounds__(256) void prep_k(const float* __restrict__ f,
                                              const int* __restrict__ eio,
                                              float* __restrict__ ws) {
    const int bid = blockIdx.x, t = threadIdx.x;
    if (bid < 512) {                     // coalesced featT transpose: 32 p-rows/block
        __shared__ float tile[32][33];
        const int p0 = bid * 32;
        #pragma unroll
        for (int rep = 0; rep < 4; ++rep) {
            const int idx = rep * 256 + t;
            const int c = idx >> 5, pl = idx & 31;
            tile[pl][c] = f[c * PIN + p0 + pl];
        }
        __syncthreads();
        #pragma unroll
        for (int rep = 0; rep < 4; ++rep) {
            const int idx = rep * 256 + t;
            const int pl = idx >> 5, c = idx & 31;
            ws[FT_OFF + (p0 + pl) * 32 + c] = tile[pl][c];
        }
    } else {                             // seg[q] = lower_bound(eio, q), one thread per q
        int* seg = (int*)ws + SEG_OFF;
        const int q = (bid - 512) * 256 + t;     // 0..4095
        int lo = 0, hi = NEV;
        while (lo < hi) { int m = (lo + hi) >> 1; if (eio[m] < q) lo = m + 1; else hi = m; }
        seg[q] = lo;
        if (q == 0) seg[POUT] = NEV;
    }
}

template <int MODE>   // 0: seg+featT in ws; 2: no ws (fallback)
__global__ __launch_bounds__(256, 2) void quadconv_mfma_k(
    const float* __restrict__ features,
    const float* __restrict__ eval_locs,
    const float* __restrict__ quad_weights,
    const float* __restrict__ W0,
    const float* __restrict__ W1,
    const float* __restrict__ W2,
    const int* __restrict__ eio,
    const int* __restrict__ eii,
    const float* __restrict__ ws,
    float* __restrict__ out)               // (4, 8, 4096)
{
    __shared__ unsigned lh[4][64 * LH_ST];   // per-wave h1 planes: [khid][eval], u32 = hi|lo
    __shared__ unsigned lw[4][32 * LW_ST];   // per-wave wg planes: [bi][eval]
    const int tid  = threadIdx.x;
    const int wid  = tid >> 6;
    const int lane = tid & 63;
    const int n    = lane & 31;
    const int hl   = lane >> 5;
    const int p    = blockIdx.x * 4 + wid;

    int start, end;
    if constexpr (MODE == 0) {
        const int* seg = (const int*)ws + SEG_OFF;
        start = seg[p]; end = seg[p + 1];
    } else {
        int lo = 0, hi = NEV;
        while (lo < hi) { int m = (lo + hi) >> 1; if (eio[m] < p) lo = m + 1; else hi = m; }
        start = lo; hi = NEV;
        while (lo < hi) { int m = (lo + hi) >> 1; if (eio[m] <= p) lo = m + 1; else hi = m; }
        end = lo;
    }

    // ---- resident A-fragments: W1^T (M=64 x K=64), truncation hi/lo split ----
    // A[m][k]: m=(lane&31)+32*mb, k=8*hl+e+16*t -> W1[k*64+m]
    bf16x8 a1hi[2][4], a1lo[2][4];
    #pragma unroll
    for (int mb = 0; mb < 2; ++mb) {
        #pragma unroll
        for (int t = 0; t < 4; ++t) {
            unsigned hw[4], lw_[4];
            #pragma unroll
            for (int i = 0; i < 4; ++i) {
                const float v0 = W1[(8 * hl + 2 * i + 16 * t) * 64 + n + 32 * mb];
                const float v1 = W1[(8 * hl + 2 * i + 1 + 16 * t) * 64 + n + 32 * mb];
                const unsigned b0 = __builtin_bit_cast(unsigned, v0);
                const unsigned b1 = __builtin_bit_cast(unsigned, v1);
                const float l0 = v0 - __builtin_bit_cast(float, b0 & 0xFFFF0000u);
                const float l1 = v1 - __builtin_bit_cast(float, b1 & 0xFFFF0000u);
                hw[i]  = __builtin_amdgcn_perm(b1, b0, SEL_HI);
                lw_[i] = __builtin_amdgcn_perm(__builtin_bit_cast(unsigned, l1),
                                               __builtin_bit_cast(unsigned, l0), SEL_HI);
            }
            a1hi[mb][t] = __builtin_bit_cast(bf16x8, make_uint4(hw[0], hw[1], hw[2], hw[3]));
            a1lo[mb][t] = __builtin_bit_cast(bf16x8, make_uint4(lw_[0], lw_[1], lw_[2], lw_[3]));
        }
    }

    // persistent accumulator T[khid, (b,i)] (64x32)
    f32x16 T[2];
    #pragma unroll
    for (int mb = 0; mb < 2; ++mb)
        #pragma unroll
        for (int r = 0; r < 16; ++r) T[mb][r] = 0.f;

    unsigned* Lhw = &lh[wid][4 * hl * LH_ST + n];        // write base (h1)
    unsigned* Lww = &lw[wid][16 * hl * LW_ST + n];       // write base (wg)
    const unsigned* Lhr = &lh[wid][n * LH_ST + 8 * hl];  // read base (GEMM2 A)
    const unsigned* Lwr = &lw[wid][n * LW_ST + 8 * hl];  // read base (GEMM2 B)

    const int nt = (end - start + 31) >> 5;

    for (int tile = 0; tile < nt; ++tile) {
        const int e  = start + tile * 32 + n;
        const bool valid = (e < end);
        const int ec = valid ? e : (end - 1);
        const float2 x = ((const float2*)eval_locs)[ec];
        const int ii = eii[ec];

        const float r2 = x.x * x.x + x.y * x.y;
        const float dd = 1.0f - 1048576.0f * r2 * r2;      // 1 - DECAY*r4 >= 0.33
        float wgt = __expf(1.0f - 1.0f / dd) * quad_weights[ii];
        if (!valid) wgt = 0.f;

        // ---- GEMM1: H1pre^T(64 x 32evals) = W1^T @ H0^T ; B built in-register ----
        f32x16 acc1[2];
        #pragma unroll
        for (int mb = 0; mb < 2; ++mb)
            #pragma unroll
            for (int r = 0; r < 16; ++r) acc1[mb][r] = 0.f;

        #pragma unroll
        for (int t = 0; t < 4; ++t) {
            const int k0 = 16 * t + 8 * hl;
            float s[8];
            #pragma unroll
            for (int q = 0; q < 8; ++q)
                s[q] = __sinf(fmaf(x.x, W0[k0 + q], x.y * W0[64 + k0 + q]));
            unsigned hw[4], lw_[4];
            #pragma unroll
            for (int i = 0; i < 4; ++i) {
                const unsigned b0 = __builtin_bit_cast(unsigned, s[2 * i]);
                const unsigned b1 = __builtin_bit_cast(unsigned, s[2 * i + 1]);
                const float l0 = s[2 * i]     - __builtin_bit_cast(float, b0 & 0xFFFF0000u);
                const float l1 = s[2 * i + 1] - __builtin_bit_cast(float, b1 & 0xFFFF0000u);
                hw[i]  = __builtin_amdgcn_perm(b1, b0, SEL_HI);
                lw_[i] = __builtin_amdgcn_perm(__builtin_bit_cast(unsigned, l1),
                                               __builtin_bit_cast(unsigned, l0), SEL_HI);
            }
            const bf16x8 bhi = __builtin_bit_cast(bf16x8, make_uint4(hw[0], hw[1], hw[2], hw[3]));
            const bf16x8 blo = __builtin_bit_cast(bf16x8, make_uint4(lw_[0], lw_[1], lw_[2], lw_[3]));
            GEMM3(acc1[0], a1hi[0][t], a1lo[0][t], bhi, blo);
            GEMM3(acc1[1], a1hi[1][t], a1lo[1][t], bhi, blo);
        }

        // ---- h1 = sin(acc1): pack hi|lo u32, write transposed plane Lh[khid][e=n] ----
        // C layout: col n, row khid = (r&3)+8*(r>>2)+4*hl+32*mb
        #pragma unroll
        for (int mb = 0; mb < 2; ++mb) {
            #pragma unroll
            for (int r = 0; r < 16; ++r) {
                const int row = ((r & 3) + 8 * (r >> 2) + 32 * mb);   // + 4*hl in base
                Lhw[row * LH_ST] = pack_hl(__sinf(acc1[mb][r]));
            }
        }

        // ---- wg[bi] = wgt * g[bi], bi = 16*hl + v; write plane Lw[bi][e=n] ----
        {
            float g[16];
            if constexpr (MODE == 0) {
                const float4* gp = (const float4*)(ws + FT_OFF + ii * 32 + 16 * hl);
                const float4 G0 = gp[0], G1 = gp[1], G2 = gp[2], G3 = gp[3];
                g[0]=G0.x; g[1]=G0.y; g[2]=G0.z; g[3]=G0.w;
                g[4]=G1.x; g[5]=G1.y; g[6]=G1.z; g[7]=G1.w;
                g[8]=G2.x; g[9]=G2.y; g[10]=G2.z; g[11]=G2.w;
                g[12]=G3.x; g[13]=G3.y; g[14]=G3.z; g[15]=G3.w;
            } else {
                #pragma unroll
                for (int v = 0; v < 16; ++v) g[v] = features[(16 * hl + v) * PIN + ii];
            }
            #pragma unroll
            for (int v = 0; v < 16; ++v) Lww[v * LW_ST] = pack_hl(wgt * g[v]);
        }

        // ---- GEMM2': T[khid,(b,i)] += h1(64 x e) @ wg(e x 32) over 32 evals ----
        #pragma unroll
        for (int kt = 0; kt < 2; ++kt) {
            const uint4 p0 = *(const uint4*)(Lwr + 16 * kt);
            const uint4 p1 = *(const uint4*)(Lwr + 16 * kt + 4);
            const bf16x8 bh = __builtin_bit_cast(bf16x8, make_uint4(
                __builtin_amdgcn_perm(p0.y, p0.x, SEL_HI),
                __builtin_amdgcn_perm(p0.w, p0.z, SEL_HI),
                __builtin_amdgcn_perm(p1.y, p1.x, SEL_HI),
                __builtin_amdgcn_perm(p1.w, p1.z, SEL_HI)));
            const bf16x8 bl = __builtin_bit_cast(bf16x8, make_uint4(
                __builtin_amdgcn_perm(p0.y, p0.x, SEL_LO),
                __builtin_amdgcn_perm(p0.w, p0.z, SEL_LO),
                __builtin_amdgcn_perm(p1.y, p1.x, SEL_LO),
                __builtin_amdgcn_perm(p1.w, p1.z, SEL_LO)));
            #pragma unroll
            for (int mb = 0; mb < 2; ++mb) {
                const uint4 q0 = *(const uint4*)(Lhr + 32 * mb * LH_ST + 16 * kt);
                const uint4 q1 = *(const uint4*)(Lhr + 32 * mb * LH_ST + 16 * kt + 4);
                const bf16x8 ah = __builtin_bit_cast(bf16x8, make_uint4(
                    __builtin_amdgcn_perm(q0.y, q0.x, SEL_HI),
                    __builtin_amdgcn_perm(q0.w, q0.z, SEL_HI),
                    __builtin_amdgcn_perm(q1.y, q1.x, SEL_HI),
                    __builtin_amdgcn_perm(q1.w, q1.z, SEL_HI)));
                const bf16x8 al = __builtin_bit_cast(bf16x8, make_uint4(
                    __builtin_amdgcn_perm(q0.y, q0.x, SEL_LO),
                    __builtin_amdgcn_perm(q0.w, q0.z, SEL_LO),
                    __builtin_amdgcn_perm(q1.y, q1.x, SEL_LO),
                    __builtin_amdgcn_perm(q1.w, q1.z, SEL_LO)));
                GEMM3(T[mb], ah, al, bh, bl);
            }
        }
    }

    // ---- epilogue: out[b,j] = sum_{khid,i} W2[khid][i*8+j] * T[khid][b*8+i] ----
    {
        const int i = n & 7, b = n >> 3;
        float pj[8];
        #pragma unroll
        for (int j = 0; j < 8; ++j) pj[j] = 0.f;
        #pragma unroll
        for (int mb = 0; mb < 2; ++mb) {
            #pragma unroll
            for (int r = 0; r < 16; ++r) {
                const int khid = (r & 3) + 8 * (r >> 2) + 4 * hl + 32 * mb;
                const float tv = T[mb][r];
                const float4 w20 = *(const float4*)(W2 + khid * 64 + i * 8);
                const float4 w21 = *(const float4*)(W2 + khid * 64 + i * 8 + 4);
                pj[0] = fmaf(tv, w20.x, pj[0]);
                pj[1] = fmaf(tv, w20.y, pj[1]);
                pj[2] = fmaf(tv, w20.z, pj[2]);
                pj[3] = fmaf(tv, w20.w, pj[3]);
                pj[4] = fmaf(tv, w21.x, pj[4]);
                pj[5] = fmaf(tv, w21.y, pj[5]);
                pj[6] = fmaf(tv, w21.z, pj[6]);
                pj[7] = fmaf(tv, w21.w, pj[7]);
            }
        }
        #pragma unroll
        for (int j = 0; j < 8; ++j) {   // reduce over i (xor 1,2,4) and hl (xor 32)
            float v = pj[j];
            v += __shfl_xor(v, 1);
            v += __shfl_xor(v, 2);
            v += __shfl_xor(v, 4);
            v += __shfl_xor(v, 32);
            pj[j] = v;
        }
        if (i == 0 && hl == 0) {
            #pragma unroll
            for (int j = 0; j < 8; ++j) out[b * (8 * POUT) + j * POUT + p] = pj[j];
        }
    }
}

extern "C" void kernel_launch(void* const* d_in, const int* in_sizes, int n_in,
                              void* d_out, int out_size, void* d_ws, size_t ws_size,
                              hipStream_t stream) {
    const float* features  = (const float*)d_in[0];
    const float* eval_locs = (const float*)d_in[1];
    const float* qw        = (const float*)d_in[2];
    const float* W0        = (const float*)d_in[3];
    const float* W1        = (const float*)d_in[4];
    const float* W2        = (const float*)d_in[5];
    const int*   eio       = (const int*)d_in[6];
    const int*   eii       = (const int*)d_in[7];
    float* out = (float*)d_out;
    float* ws  = (float*)d_ws;

    const size_t need0 = (size_t)(FT_OFF + FT_FLOATS) * 4;
    if (ws_size >= need0) {
        prep_k<<<512 + POUT / 256, 256, 0, stream>>>(features, eio, ws);
        quadconv_mfma_k<0><<<POUT / 4, 256, 0, stream>>>(features, eval_locs, qw, W0, W1, W2,
                                                         eio, eii, ws, out);
    } else {
        quadconv_mfma_k<2><<<POUT / 4, 256, 0, stream>>>(features, eval_locs, qw, W0, W1, W2,
                                                         eio, eii, ws, out);
    }
}